// Round 16
// baseline (748.173 us; speedup 1.0000x reference)
//
#include <hip/hip_runtime.h>

// Round 16: R14 base + 1-super-tile software-pipeline SKEW:
//   iter u: QK(u) [independent MFMAs] || softmax+P+PV(u-1) [VALU/LDS/MFMA]
// -> compiler can interleave the dependent softmax chain with QK's MFMA bubbles.
// Base-2 softmax (log2e folded into q scale, native exp2f). No main-loop barriers.
// Block 256 = 4 waves (1/SIMD, 512-reg budget) = 2 qw(32q) x 2 g(2048 keys).
//   d_in: 0=x f32, 1=mask i32, 2=Wk, 3=Wq, 4=Wv
// ws (f16): qT [BT/32][8192] | kT [BT/16][4096] | vT [BT/16][4096]
//   qT: [(qh*8+kc)*512 + l4*128 + tok*8 + j]  (x log2e/16 folded)
//   kT: [kc*512 + ch*128 + key*8 + j]   <-> K[16t+key][kc*32+ch*8+j]
//   vT: [dt*512 + kh*256 + d31*8 + j]   <-> V^T[dt*32+d31][16t+kh*8+j]

typedef __attribute__((ext_vector_type(8)))  _Float16 f16x8;
typedef __attribute__((ext_vector_type(4)))  _Float16 f16x4;
typedef __attribute__((ext_vector_type(4)))  float    f32x4;
typedef __attribute__((ext_vector_type(16))) float    f32x16;

constexpr int Bb = 4;
constexpr int Tt = 4096;
constexpr int Cc = 256;
constexpr int BT = Bb * Tt;

#define MFMA16(a, b, c) __builtin_amdgcn_mfma_f32_16x16x32_f16((a), (b), (c), 0, 0, 0)
#define MFMA32(a, b, c) __builtin_amdgcn_mfma_f32_32x32x16_f16((a), (b), (c), 0, 0, 0)

// ---------------- Kernel A: fused QKV projection ----------------
__global__ __launch_bounds__(256) void qkv_proj(
    const float* __restrict__ x,
    const float* __restrict__ Wq, const float* __restrict__ Wk,
    const float* __restrict__ Wv,
    _Float16* __restrict__ qo, _Float16* __restrict__ ko,
    _Float16* __restrict__ vto)
{
    extern __shared__ _Float16 sm[];
    _Float16* xs = sm;              // [128][264]
    _Float16* wsm = sm + 128 * 264; // [128][264]

    const int tid = threadIdx.x;
    const int m0  = blockIdx.x * 128;
    const int ny  = blockIdx.y;
    const int mat = ny >> 1;              // 0=q 1=k 2=v
    const int d0  = (ny & 1) * 128;
    const float* W = (mat == 0) ? Wq : (mat == 1 ? Wk : Wv);

#pragma unroll
    for (int i = 0; i < 32; ++i) {
        int flat = i * 256 + tid;
        int r = flat >> 6, c4 = (flat & 63) << 2;
        float4 v = *reinterpret_cast<const float4*>(x + (size_t)(m0 + r) * Cc + c4);
        f16x4 h = { (_Float16)v.x, (_Float16)v.y, (_Float16)v.z, (_Float16)v.w };
        *reinterpret_cast<f16x4*>(xs + r * 264 + c4) = h;
    }
#pragma unroll
    for (int i = 0; i < 32; ++i) {
        int flat = i * 256 + tid;
        int r = flat >> 6, c4 = (flat & 63) << 2;
        float4 v = *reinterpret_cast<const float4*>(W + (size_t)(d0 + r) * Cc + c4);
        f16x4 h = { (_Float16)v.x, (_Float16)v.y, (_Float16)v.z, (_Float16)v.w };
        *reinterpret_cast<f16x4*>(wsm + r * 264 + c4) = h;
    }
    __syncthreads();

    const int w = tid >> 6, lane = tid & 63;
    const int lr = lane & 15, lg = lane >> 4;

    f32x4 acc[2][8] = {};

#pragma unroll
    for (int kc = 0; kc < 8; ++kc) {
        const int c0 = kc * 32 + lg * 8;
        f16x8 xf[2], wf[8];
#pragma unroll
        for (int mb = 0; mb < 2; ++mb)
            xf[mb] = *reinterpret_cast<const f16x8*>(xs + (w * 32 + mb * 16 + lr) * 264 + c0);
#pragma unroll
        for (int db = 0; db < 8; ++db)
            wf[db] = *reinterpret_cast<const f16x8*>(wsm + (db * 16 + lr) * 264 + c0);
        if (mat != 2) {
#pragma unroll
            for (int mb = 0; mb < 2; ++mb)
#pragma unroll
                for (int db = 0; db < 8; ++db)
                    acc[mb][db] = MFMA16(wf[db], xf[mb], acc[mb][db]);   // D[d][tok]
        } else {
#pragma unroll
            for (int mb = 0; mb < 2; ++mb)
#pragma unroll
                for (int db = 0; db < 8; ++db)
                    acc[mb][db] = MFMA16(xf[mb], wf[db], acc[mb][db]);   // D[tok][d]
        }
    }

    if (mat != 2) {
        // q scale: 1/sqrt(256) * log2(e)  (softmax in base-2 domain)
        const float sc = (mat == 0) ? 0.0625f * 1.44269504f : 1.0f;
        const int jj  = (lg & 1) * 4;
#pragma unroll
        for (int mb = 0; mb < 2; ++mb)
#pragma unroll
            for (int db = 0; db < 8; ++db) {
                int m  = m0 + w * 32 + mb * 16 + lr;
                int c  = d0 + db * 16 + lg * 4;
                int kc = c >> 5;
                int ch = (c >> 3) & 3;
                f32x4 a = acc[mb][db];
                f16x4 h = { (_Float16)(a.x * sc), (_Float16)(a.y * sc),
                            (_Float16)(a.z * sc), (_Float16)(a.w * sc) };
                if (mat == 0) {
                    size_t off = (size_t)(m >> 5) * 8192 + (((m >> 4) & 1) * 8 + kc) * 512
                               + ch * 128 + (m & 15) * 8 + jj;
                    *reinterpret_cast<f16x4*>(qo + off) = h;
                } else {
                    size_t off = (size_t)(m >> 4) * 4096 + kc * 512
                               + ch * 128 + (m & 15) * 8 + jj;
                    *reinterpret_cast<f16x4*>(ko + off) = h;
                }
            }
    } else {
        const int jj = (lg & 1) * 4;
        const int kh = (lg >> 1) & 1;
#pragma unroll
        for (int mb = 0; mb < 2; ++mb)
#pragma unroll
            for (int db = 0; db < 8; ++db) {
                int d = d0 + db * 16 + lr;
                int m = m0 + w * 32 + mb * 16 + lg * 4;
                f32x4 a = acc[mb][db];
                f16x4 h = { (_Float16)a.x, (_Float16)a.y, (_Float16)a.z, (_Float16)a.w };
                size_t off = (size_t)(m >> 4) * 4096 + (d >> 5) * 512
                           + kh * 256 + (d & 31) * 8 + jj;
                *reinterpret_cast<f16x4*>(vto + off) = h;
            }
    }
}

// ---------------- Kernel B: register-resident, software-skewed ----------------
// LDS (bytes): [0,10240) per-warp P [4][32][40] f16 | [10240,10752) mex f32[4][32]
//              [10752,11264) lex | [11264,77312) oex f32[2 qw][32 q][258]
__global__ __launch_bounds__(256, 1) void attn_kernel(
    const _Float16* __restrict__ qb, const _Float16* __restrict__ kb,
    const _Float16* __restrict__ vtb, const int* __restrict__ mask,
    float* __restrict__ outp)
{
    extern __shared__ char smraw[];
    float* mex  = (float*)(smraw + 10240);
    float* lex  = (float*)(smraw + 10752);
    float* oexf = (float*)(smraw + 11264);

    const int tid = threadIdx.x, w = tid >> 6, lane = tid & 63;
    const int qw = w >> 1, g = w & 1;
    const int l15 = lane & 15, l4 = lane >> 4;
    const int l31 = lane & 31, l5 = lane >> 5;

    const int bid = blockIdx.x;
    const int b   = (bid & 7) >> 1;                    // batch -> XCD pair
    const int qt  = ((bid >> 3) << 1) | (bid & 1);     // [0,64)
    const int q0  = qt * 64;
    const size_t base = (size_t)b * Tt * Cc;
    const int* maskb = mask + (size_t)b * Tt;
    const _Float16* kTb = kb + base;
    const _Float16* vTb = vtb + base;

    // Q fragments: Q[q0 + qw*32 + qh*16 + l15][kc*32 + l4*8 + j]  (x log2e/16)
    f16x8 qf[2][8];
    {
        const _Float16* qTb = qb + (size_t)(b * 128 + qt * 2 + qw) * 8192;
#pragma unroll
        for (int qh = 0; qh < 2; ++qh)
#pragma unroll
            for (int kc = 0; kc < 8; ++kc)
                qf[qh][kc] = *reinterpret_cast<const f16x8*>(
                    qTb + (qh * 8 + kc) * 512 + l4 * 128 + l15 * 8);
    }

    _Float16* pw = (_Float16*)smraw + w * 1280;        // [32][40] private bounce

    f32x16 o[8] = {};                  // O^T[d = dt*32+(r&3)+8*(r>>2)+4*l5][q=l31]
    float m0r = -60.f, m1r = -60.f, l0r = 0.f, l1r = 0.f;

    auto LOADK = [&](f16x8 (&kr)[8], int tile) {
        const _Float16* kp = kTb + (size_t)tile * 4096 + l4 * 128 + l15 * 8;
#pragma unroll
        for (int kc = 0; kc < 8; ++kc)
            kr[kc] = *reinterpret_cast<const f16x8*>(kp + kc * 512);
    };
    auto LOADV = [&](f16x8 (&vr)[8], int tile) {
        const _Float16* vp = vTb + (size_t)tile * 4096 + l5 * 256 + l31 * 8;
#pragma unroll
        for (int dt = 0; dt < 8; ++dt)
            vr[dt] = *reinterpret_cast<const f16x8*>(vp + dt * 512);
    };
    auto QK = [&](f16x8 (&kr)[8], int4 mc, f32x4& s0, f32x4& s1) {
        s0 = (f32x4){ 0.f, 0.f, 0.f, 0.f };
        s1 = (f32x4){ 0.f, 0.f, 0.f, 0.f };
#pragma unroll
        for (int kc = 0; kc < 8; ++kc) {
            s0 = MFMA16(kr[kc], qf[0][kc], s0);
            s1 = MFMA16(kr[kc], qf[1][kc], s1);
        }
        if (mc.x == 0) { s0[0] = -1e30f; s1[0] = -1e30f; }
        if (mc.y == 0) { s0[1] = -1e30f; s1[1] = -1e30f; }
        if (mc.z == 0) { s0[2] = -1e30f; s1[2] = -1e30f; }
        if (mc.w == 0) { s0[3] = -1e30f; s1[3] = -1e30f; }
    };

    // softmax + P-pack + PV for one 32-key super-tile (S of tiles A,B; V regs)
    f16x8 vA[8], vB[8];
    auto SMPV = [&](f32x4& sa0, f32x4& sa1, f32x4& sb0, f32x4& sb1) {
        float t0 = fmaxf(fmaxf(fmaxf(sa0[0], sa0[1]), fmaxf(sa0[2], sa0[3])),
                         fmaxf(fmaxf(sb0[0], sb0[1]), fmaxf(sb0[2], sb0[3])));
        float t1 = fmaxf(fmaxf(fmaxf(sa1[0], sa1[1]), fmaxf(sa1[2], sa1[3])),
                         fmaxf(fmaxf(sb1[0], sb1[1]), fmaxf(sb1[2], sb1[3])));
        t0 = fmaxf(t0, __shfl_xor(t0, 16, 64)); t0 = fmaxf(t0, __shfl_xor(t0, 32, 64));
        t1 = fmaxf(t1, __shfl_xor(t1, 16, 64)); t1 = fmaxf(t1, __shfl_xor(t1, 32, 64));

        if (__any(t0 > m0r + 11.54f || t1 > m1r + 11.54f)) {   // defer-max (base-2)
            float mn0 = fmaxf(m0r, t0), mn1 = fmaxf(m1r, t1);
            float c0 = exp2f(m0r - mn0), c1 = exp2f(m1r - mn1);
            m0r = mn0; m1r = mn1; l0r *= c0; l1r *= c1;
            float cs = (lane & 16) ? c1 : c0;              // o cols: q = l31
#pragma unroll
            for (int dt = 0; dt < 8; ++dt) o[dt] *= cs;
        }

        float rs0 = 0.f, rs1 = 0.f;
#pragma unroll
        for (int r = 0; r < 4; ++r) {
            float p;
            p = exp2f(sa0[r] - m0r); sa0[r] = p; rs0 += p;
            p = exp2f(sb0[r] - m0r); sb0[r] = p; rs0 += p;
            p = exp2f(sa1[r] - m1r); sa1[r] = p; rs1 += p;
            p = exp2f(sb1[r] - m1r); sb1[r] = p; rs1 += p;
        }
        rs0 += __shfl_xor(rs0, 16, 64); rs0 += __shfl_xor(rs0, 32, 64);
        rs1 += __shfl_xor(rs1, 16, 64); rs1 += __shfl_xor(rs1, 32, 64);
        l0r += rs0; l1r += rs1;

        {
            f16x4 h;
            h = (f16x4){ (_Float16)sa0[0], (_Float16)sa0[1], (_Float16)sa0[2], (_Float16)sa0[3] };
            *reinterpret_cast<f16x4*>(pw + l15 * 40 + l4 * 4) = h;
            h = (f16x4){ (_Float16)sb0[0], (_Float16)sb0[1], (_Float16)sb0[2], (_Float16)sb0[3] };
            *reinterpret_cast<f16x4*>(pw + l15 * 40 + 16 + l4 * 4) = h;
            h = (f16x4){ (_Float16)sa1[0], (_Float16)sa1[1], (_Float16)sa1[2], (_Float16)sa1[3] };
            *reinterpret_cast<f16x4*>(pw + (16 + l15) * 40 + l4 * 4) = h;
            h = (f16x4){ (_Float16)sb1[0], (_Float16)sb1[1], (_Float16)sb1[2], (_Float16)sb1[3] };
            *reinterpret_cast<f16x4*>(pw + (16 + l15) * 40 + 16 + l4 * 4) = h;
        }
        f16x8 pf0 = *reinterpret_cast<const f16x8*>(pw + l31 * 40 + l5 * 8);
        f16x8 pf1 = *reinterpret_cast<const f16x8*>(pw + l31 * 40 + 16 + l5 * 8);

#pragma unroll
        for (int dt = 0; dt < 8; ++dt) {
            o[dt] = MFMA32(vA[dt], pf0, o[dt]);
            o[dt] = MFMA32(vB[dt], pf1, o[dt]);
        }
    };

    // ---- skewed main loop: QK(u) || SMPV(u-1). No barriers. ----
    f16x8 kA[8], kB[8];
    int4 mnA, mnB;
    f32x4 spA0, spA1, spB0, spB1;
    const int ktb = g * 128;                 // this wave's tiles [ktb, ktb+128)

    // prologue: u = 0
    LOADK(kA, ktb); LOADK(kB, ktb + 1);
    LOADV(vA, ktb); LOADV(vB, ktb + 1);
    {
        int4 m0_ = *reinterpret_cast<const int4*>(maskb + ktb * 16 + l4 * 4);
        int4 m1_ = *reinterpret_cast<const int4*>(maskb + (ktb + 1) * 16 + l4 * 4);
        QK(kA, m0_, spA0, spA1);
        QK(kB, m1_, spB0, spB1);
    }
    LOADK(kA, ktb + 2); LOADK(kB, ktb + 3);
    mnA = *reinterpret_cast<const int4*>(maskb + (ktb + 2) * 16 + l4 * 4);
    mnB = *reinterpret_cast<const int4*>(maskb + (ktb + 3) * 16 + l4 * 4);

#pragma unroll 1
    for (int u = 1; u < 64; ++u) {
        // QK(u): independent MFMA work the scheduler can interleave with SMPV(u-1)
        f32x4 snA0, snA1, snB0, snB1;
        QK(kA, mnA, snA0, snA1);
        QK(kB, mnB, snB0, snB1);

        const int tA = (u < 63) ? (ktb + 2 * u + 2) : ktb;   // last: dummy
        const int tB = (u < 63) ? (ktb + 2 * u + 3) : ktb;
        LOADK(kA, tA); LOADK(kB, tB);
        int4 mtA = *reinterpret_cast<const int4*>(maskb + tA * 16 + l4 * 4);
        int4 mtB = *reinterpret_cast<const int4*>(maskb + tB * 16 + l4 * 4);

        // softmax + P + PV for super-tile u-1 (uses vA/vB = tiles 2(u-1),2(u-1)+1)
        SMPV(spA0, spA1, spB0, spB1);

        // V for super-tile u (consumed by SMPV in iter u+1)
        LOADV(vA, ktb + 2 * u); LOADV(vB, ktb + 2 * u + 1);

        spA0 = snA0; spA1 = snA1; spB0 = snB0; spB1 = snB1;
        mnA = mtA; mnB = mtB;
    }
    // epilogue of skew: final SMPV for u=63's S (vA/vB hold tiles 126,127)
    SMPV(spA0, spA1, spB0, spB1);

    // ---- epilogue: 2-way split-K merge ----
    __syncthreads();
    if (l4 == 0) {
        mex[w * 32 + l15]      = m0r;  mex[w * 32 + 16 + l15] = m1r;
        lex[w * 32 + l15]      = l0r;  lex[w * 32 + 16 + l15] = l1r;
    }
    __syncthreads();

    {
        float mq  = (lane & 16) ? m1r : m0r;
        float mA2 = mex[(qw * 2 + 0) * 32 + l31];
        float mB2 = mex[(qw * 2 + 1) * 32 + l31];
        float mst = fmaxf(mA2, mB2);
        float osc = exp2f(mq - mst);
        float* oq = oexf + qw * (32 * 258);
        if (g == 1) {
#pragma unroll
            for (int dt = 0; dt < 8; ++dt)
#pragma unroll
                for (int r = 0; r < 16; ++r) {
                    int d = dt * 32 + (r & 3) + 8 * (r >> 2) + 4 * l5;
                    oq[l31 * 258 + d] = o[dt][r] * osc;
                }
        }
        __syncthreads();
        if (g == 0) {
#pragma unroll
            for (int dt = 0; dt < 8; ++dt)
#pragma unroll
                for (int r = 0; r < 16; ++r) {
                    int d = dt * 32 + (r & 3) + 8 * (r >> 2) + 4 * l5;
                    oq[l31 * 258 + d] += o[dt][r] * osc;
                }
        }
        __syncthreads();
    }

    // readout: q = tid>>2 in [0,64), dseg = (tid&3)*64
    {
        const int q = tid >> 2, ds0 = (tid & 3) * 64;
        const int qws = q >> 5, ql = q & 31;
        float mA2 = mex[(qws * 2 + 0) * 32 + ql];
        float mB2 = mex[(qws * 2 + 1) * 32 + ql];
        float ms  = fmaxf(mA2, mB2);
        float lt  = lex[(qws * 2 + 0) * 32 + ql] * exp2f(mA2 - ms)
                  + lex[(qws * 2 + 1) * 32 + ql] * exp2f(mB2 - ms);
        float inv = 1.f / lt;
        const float* src = oexf + qws * (32 * 258) + ql * 258 + ds0;
        float* dst = outp + base + (size_t)(q0 + q) * Cc + ds0;
#pragma unroll
        for (int i = 0; i < 16; ++i) {
            f32x4 a = *reinterpret_cast<const f32x4*>(src + 4 * i);
            a[0] *= inv; a[1] *= inv; a[2] *= inv; a[3] *= inv;
            *reinterpret_cast<f32x4*>(dst + 4 * i) = a;
        }
    }
}

extern "C" void kernel_launch(void* const* d_in, const int* in_sizes, int n_in,
                              void* d_out, int out_size, void* d_ws, size_t ws_size,
                              hipStream_t stream)
{
    (void)in_sizes; (void)n_in; (void)out_size; (void)ws_size;
    const float* x   = (const float*)d_in[0];
    const int*  mask = (const int*)d_in[1];
    const float* Wk  = (const float*)d_in[2];
    const float* Wq  = (const float*)d_in[3];
    const float* Wv  = (const float*)d_in[4];
    float* out = (float*)d_out;

    _Float16* q  = (_Float16*)d_ws;
    _Float16* k  = q + (size_t)BT * Cc;
    _Float16* vt = k + (size_t)BT * Cc;

    dim3 gA(128, 6), blkA(256);
    size_t ldsA = (size_t)(128 + 128) * 264 * sizeof(_Float16);
    qkv_proj<<<gA, blkA, ldsA, stream>>>(x, Wq, Wk, Wv, q, k, vt);

    dim3 gB(256), blkB(256);
    size_t ldsB = 77312;
    attn_kernel<<<gB, blkB, ldsB, stream>>>(q, k, vt, mask, out);
}

// Round 17
// 138.878 us; speedup vs baseline: 5.3873x; 5.3873x over previous
//
#include <hip/hip_runtime.h>

// Round 17: REVERT to R12 (best: 128.5 us) + s_setprio around MFMA clusters
// (m191: setprio helps attn when waves drift independently — exactly R12's regime).
// Block = 256 thr = 4 waves (1/SIMD, 512-reg budget), K/V L2->reg ping-pong,
// zero main-loop barriers, 2 qw(32q) x 2 g(2048 keys), grid 256.
//   d_in: 0=x f32, 1=mask i32, 2=Wk, 3=Wq, 4=Wv
// ws (f16): qT [BT/32][8192] | kT [BT/16][4096] | vT [BT/16][4096]
//   qT: [(qh*8+kc)*512 + l4*128 + tok*8 + j]  (x1/16 folded)
//   kT: [kc*512 + ch*128 + key*8 + j]   <-> K[16t+key][kc*32+ch*8+j]
//   vT: [dt*512 + kh*256 + d31*8 + j]   <-> V^T[dt*32+d31][16t+kh*8+j]

typedef __attribute__((ext_vector_type(8)))  _Float16 f16x8;
typedef __attribute__((ext_vector_type(4)))  _Float16 f16x4;
typedef __attribute__((ext_vector_type(4)))  float    f32x4;
typedef __attribute__((ext_vector_type(16))) float    f32x16;

constexpr int Bb = 4;
constexpr int Tt = 4096;
constexpr int Cc = 256;
constexpr int BT = Bb * Tt;

#define MFMA16(a, b, c) __builtin_amdgcn_mfma_f32_16x16x32_f16((a), (b), (c), 0, 0, 0)
#define MFMA32(a, b, c) __builtin_amdgcn_mfma_f32_32x32x16_f16((a), (b), (c), 0, 0, 0)

// ---------------- Kernel A: fused QKV projection ----------------
__global__ __launch_bounds__(256) void qkv_proj(
    const float* __restrict__ x,
    const float* __restrict__ Wq, const float* __restrict__ Wk,
    const float* __restrict__ Wv,
    _Float16* __restrict__ qo, _Float16* __restrict__ ko,
    _Float16* __restrict__ vto)
{
    extern __shared__ _Float16 sm[];
    _Float16* xs = sm;              // [128][264]
    _Float16* wsm = sm + 128 * 264; // [128][264]

    const int tid = threadIdx.x;
    const int m0  = blockIdx.x * 128;
    const int ny  = blockIdx.y;
    const int mat = ny >> 1;              // 0=q 1=k 2=v
    const int d0  = (ny & 1) * 128;
    const float* W = (mat == 0) ? Wq : (mat == 1 ? Wk : Wv);

#pragma unroll
    for (int i = 0; i < 32; ++i) {
        int flat = i * 256 + tid;
        int r = flat >> 6, c4 = (flat & 63) << 2;
        float4 v = *reinterpret_cast<const float4*>(x + (size_t)(m0 + r) * Cc + c4);
        f16x4 h = { (_Float16)v.x, (_Float16)v.y, (_Float16)v.z, (_Float16)v.w };
        *reinterpret_cast<f16x4*>(xs + r * 264 + c4) = h;
    }
#pragma unroll
    for (int i = 0; i < 32; ++i) {
        int flat = i * 256 + tid;
        int r = flat >> 6, c4 = (flat & 63) << 2;
        float4 v = *reinterpret_cast<const float4*>(W + (size_t)(d0 + r) * Cc + c4);
        f16x4 h = { (_Float16)v.x, (_Float16)v.y, (_Float16)v.z, (_Float16)v.w };
        *reinterpret_cast<f16x4*>(wsm + r * 264 + c4) = h;
    }
    __syncthreads();

    const int w = tid >> 6, lane = tid & 63;
    const int lr = lane & 15, lg = lane >> 4;

    f32x4 acc[2][8] = {};

#pragma unroll
    for (int kc = 0; kc < 8; ++kc) {
        const int c0 = kc * 32 + lg * 8;
        f16x8 xf[2], wf[8];
#pragma unroll
        for (int mb = 0; mb < 2; ++mb)
            xf[mb] = *reinterpret_cast<const f16x8*>(xs + (w * 32 + mb * 16 + lr) * 264 + c0);
#pragma unroll
        for (int db = 0; db < 8; ++db)
            wf[db] = *reinterpret_cast<const f16x8*>(wsm + (db * 16 + lr) * 264 + c0);
        if (mat != 2) {
#pragma unroll
            for (int mb = 0; mb < 2; ++mb)
#pragma unroll
                for (int db = 0; db < 8; ++db)
                    acc[mb][db] = MFMA16(wf[db], xf[mb], acc[mb][db]);   // D[d][tok]
        } else {
#pragma unroll
            for (int mb = 0; mb < 2; ++mb)
#pragma unroll
                for (int db = 0; db < 8; ++db)
                    acc[mb][db] = MFMA16(xf[mb], wf[db], acc[mb][db]);   // D[tok][d]
        }
    }

    if (mat != 2) {
        const float sc = (mat == 0) ? 0.0625f : 1.0f;
        const int jj  = (lg & 1) * 4;
#pragma unroll
        for (int mb = 0; mb < 2; ++mb)
#pragma unroll
            for (int db = 0; db < 8; ++db) {
                int m  = m0 + w * 32 + mb * 16 + lr;
                int c  = d0 + db * 16 + lg * 4;
                int kc = c >> 5;
                int ch = (c >> 3) & 3;
                f32x4 a = acc[mb][db];
                f16x4 h = { (_Float16)(a.x * sc), (_Float16)(a.y * sc),
                            (_Float16)(a.z * sc), (_Float16)(a.w * sc) };
                if (mat == 0) {
                    size_t off = (size_t)(m >> 5) * 8192 + (((m >> 4) & 1) * 8 + kc) * 512
                               + ch * 128 + (m & 15) * 8 + jj;
                    *reinterpret_cast<f16x4*>(qo + off) = h;
                } else {
                    size_t off = (size_t)(m >> 4) * 4096 + kc * 512
                               + ch * 128 + (m & 15) * 8 + jj;
                    *reinterpret_cast<f16x4*>(ko + off) = h;
                }
            }
    } else {
        const int jj = (lg & 1) * 4;
        const int kh = (lg >> 1) & 1;
#pragma unroll
        for (int mb = 0; mb < 2; ++mb)
#pragma unroll
            for (int db = 0; db < 8; ++db) {
                int d = d0 + db * 16 + lr;
                int m = m0 + w * 32 + mb * 16 + lg * 4;
                f32x4 a = acc[mb][db];
                f16x4 h = { (_Float16)a.x, (_Float16)a.y, (_Float16)a.z, (_Float16)a.w };
                size_t off = (size_t)(m >> 4) * 4096 + (d >> 5) * 512
                           + kh * 256 + (d & 31) * 8 + jj;
                *reinterpret_cast<f16x4*>(vto + off) = h;
            }
    }
}

// ---------------- Kernel B: register-resident flash attention ----------------
// LDS (bytes): [0,6144) per-warp P [4][32][24] f16 | [6144,6656) mex f32[4][32]
//              [6656,7168) lex | [8192,74240) oex f32[2 qw][32 q][258]
__global__ __launch_bounds__(256, 1) void attn_kernel(
    const _Float16* __restrict__ qb, const _Float16* __restrict__ kb,
    const _Float16* __restrict__ vtb, const int* __restrict__ mask,
    float* __restrict__ outp)
{
    extern __shared__ char smraw[];
    float* mex  = (float*)(smraw + 6144);
    float* lex  = (float*)(smraw + 6656);
    float* oexf = (float*)(smraw + 8192);

    const int tid = threadIdx.x, w = tid >> 6, lane = tid & 63;
    const int qw = w >> 1, g = w & 1;
    const int l15 = lane & 15, l4 = lane >> 4;
    const int l31 = lane & 31, l5 = lane >> 5;

    const int bid = blockIdx.x;
    const int b   = (bid & 7) >> 1;                    // batch -> XCD pair
    const int qt  = ((bid >> 3) << 1) | (bid & 1);     // [0,64)
    const int q0  = qt * 64;
    const size_t base = (size_t)b * Tt * Cc;
    const int* maskb = mask + (size_t)b * Tt;
    const _Float16* kTb = kb + base;
    const _Float16* vTb = vtb + base;

    // Q fragments: Q[q0 + qw*32 + qh*16 + l15][kc*32 + l4*8 + j]  (x1/16)
    f16x8 qf[2][8];
    {
        const _Float16* qTb = qb + (size_t)(b * 128 + qt * 2 + qw) * 8192;
#pragma unroll
        for (int qh = 0; qh < 2; ++qh)
#pragma unroll
            for (int kc = 0; kc < 8; ++kc)
                qf[qh][kc] = *reinterpret_cast<const f16x8*>(
                    qTb + (qh * 8 + kc) * 512 + l4 * 128 + l15 * 8);
    }

    _Float16* pw = (_Float16*)smraw + w * 768;         // [32][24] private bounce

    f32x16 o[8] = {};                  // O^T[d = dt*32+(r&3)+8*(r>>2)+4*l5][q=l31]
    float m0r = -60.f, m1r = -60.f, l0r = 0.f, l1r = 0.f;

    // K/V/mask tile -> registers (all L2-resident; R8 tiled layouts)
    auto LOADT = [&](f16x8 (&kr)[8], f16x8 (&vr)[8], int4& mc, int tile) {
        const _Float16* kp = kTb + (size_t)tile * 4096 + l4 * 128 + l15 * 8;
#pragma unroll
        for (int kc = 0; kc < 8; ++kc)
            kr[kc] = *reinterpret_cast<const f16x8*>(kp + kc * 512);
        const _Float16* vp = vTb + (size_t)tile * 4096 + l5 * 256 + l31 * 8;
#pragma unroll
        for (int dt = 0; dt < 8; ++dt)
            vr[dt] = *reinterpret_cast<const f16x8*>(vp + dt * 512);
        mc = *reinterpret_cast<const int4*>(maskb + tile * 16 + l4 * 4);
    };

    auto COMPUTE = [&](f16x8 (&kr)[8], f16x8 (&vr)[8], int4 mc) {
        // QK: S^T[key = l4*4 + r][q = qh*16 + l15]
        f32x4 s40 = { 0.f, 0.f, 0.f, 0.f }, s41 = { 0.f, 0.f, 0.f, 0.f };
        __builtin_amdgcn_s_setprio(1);
#pragma unroll
        for (int kc = 0; kc < 8; ++kc) {
            s40 = MFMA16(kr[kc], qf[0][kc], s40);
            s41 = MFMA16(kr[kc], qf[1][kc], s41);
        }
        __builtin_amdgcn_s_setprio(0);
        if (mc.x == 0) { s40[0] = -1e30f; s41[0] = -1e30f; }
        if (mc.y == 0) { s40[1] = -1e30f; s41[1] = -1e30f; }
        if (mc.z == 0) { s40[2] = -1e30f; s41[2] = -1e30f; }
        if (mc.w == 0) { s40[3] = -1e30f; s41[3] = -1e30f; }

        // online softmax per qh (q = l15; keys across l4 groups)
        float t0 = fmaxf(fmaxf(s40[0], s40[1]), fmaxf(s40[2], s40[3]));
        float t1 = fmaxf(fmaxf(s41[0], s41[1]), fmaxf(s41[2], s41[3]));
        t0 = fmaxf(t0, __shfl_xor(t0, 16, 64)); t0 = fmaxf(t0, __shfl_xor(t0, 32, 64));
        t1 = fmaxf(t1, __shfl_xor(t1, 16, 64)); t1 = fmaxf(t1, __shfl_xor(t1, 32, 64));

        if (__any(t0 > m0r + 8.f || t1 > m1r + 8.f)) {     // defer-max
            float mn0 = fmaxf(m0r, t0), mn1 = fmaxf(m1r, t1);
            float c0 = __expf(m0r - mn0), c1 = __expf(m1r - mn1);
            m0r = mn0; m1r = mn1; l0r *= c0; l1r *= c1;
            float cs = (lane & 16) ? c1 : c0;              // o cols: q = l31
#pragma unroll
            for (int dt = 0; dt < 8; ++dt) o[dt] *= cs;
        }

        float rs0 = 0.f, rs1 = 0.f;
#pragma unroll
        for (int r = 0; r < 4; ++r) {
            float p0 = __expf(s40[r] - m0r); s40[r] = p0; rs0 += p0;
            float p1 = __expf(s41[r] - m1r); s41[r] = p1; rs1 += p1;
        }
        rs0 += __shfl_xor(rs0, 16, 64); rs0 += __shfl_xor(rs0, 32, 64);
        rs1 += __shfl_xor(rs1, 16, 64); rs1 += __shfl_xor(rs1, 32, 64);
        l0r += rs0; l1r += rs1;

        // P -> pw[q][k] f16; reread as PV B-frag (private, in-wave lgkm-ordered)
        {
            f16x4 h0 = { (_Float16)s40[0], (_Float16)s40[1], (_Float16)s40[2], (_Float16)s40[3] };
            f16x4 h1 = { (_Float16)s41[0], (_Float16)s41[1], (_Float16)s41[2], (_Float16)s41[3] };
            *reinterpret_cast<f16x4*>(pw + l15 * 24 + l4 * 4)        = h0;
            *reinterpret_cast<f16x4*>(pw + (16 + l15) * 24 + l4 * 4) = h1;
        }
        f16x8 pf = *reinterpret_cast<const f16x8*>(pw + l31 * 24 + l5 * 8);

        // PV: O^T += V^T P^T  (V frags straight from registers)
        __builtin_amdgcn_s_setprio(1);
#pragma unroll
        for (int dt = 0; dt < 8; ++dt)
            o[dt] = MFMA32(vr[dt], pf, o[dt]);
        __builtin_amdgcn_s_setprio(0);
    };

    // main loop: 128 tiles of 16 keys, register ping-pong, NO barriers
    f16x8 kA[8], vA[8], kB[8], vB[8];
    int4 mA_, mB_;
    const int ktb = g * 128;                 // this warp's tiles [ktb, ktb+128)
    LOADT(kA, vA, mA_, ktb);
#pragma unroll 1
    for (int t2 = 0; t2 < 64; ++t2) {
        LOADT(kB, vB, mB_, ktb + 2 * t2 + 1);
        COMPUTE(kA, vA, mA_);
        LOADT(kA, vA, mA_, (2 * t2 + 2 < 128) ? (ktb + 2 * t2 + 2) : ktb);  // last: dummy
        COMPUTE(kB, vB, mB_);
    }

    // ---- epilogue: 2-way split-K merge ----
    __syncthreads();
    if (l4 == 0) {
        mex[w * 32 + l15]      = m0r;  mex[w * 32 + 16 + l15] = m1r;
        lex[w * 32 + l15]      = l0r;  lex[w * 32 + 16 + l15] = l1r;
    }
    __syncthreads();

    {
        float mq  = (lane & 16) ? m1r : m0r;
        float mA2 = mex[(qw * 2 + 0) * 32 + l31];
        float mB2 = mex[(qw * 2 + 1) * 32 + l31];
        float mst = fmaxf(mA2, mB2);
        float osc = __expf(mq - mst);
        float* oq = oexf + qw * (32 * 258);
        if (g == 1) {
#pragma unroll
            for (int dt = 0; dt < 8; ++dt)
#pragma unroll
                for (int r = 0; r < 16; ++r) {
                    int d = dt * 32 + (r & 3) + 8 * (r >> 2) + 4 * l5;
                    oq[l31 * 258 + d] = o[dt][r] * osc;
                }
        }
        __syncthreads();
        if (g == 0) {
#pragma unroll
            for (int dt = 0; dt < 8; ++dt)
#pragma unroll
                for (int r = 0; r < 16; ++r) {
                    int d = dt * 32 + (r & 3) + 8 * (r >> 2) + 4 * l5;
                    oq[l31 * 258 + d] += o[dt][r] * osc;
                }
        }
        __syncthreads();
    }

    // readout: 256 threads -> q = tid>>2 in [0,64), dseg = (tid&3)*64
    {
        const int q = tid >> 2, ds0 = (tid & 3) * 64;
        const int qws = q >> 5, ql = q & 31;
        float mA2 = mex[(qws * 2 + 0) * 32 + ql];
        float mB2 = mex[(qws * 2 + 1) * 32 + ql];
        float ms  = fmaxf(mA2, mB2);
        float lt  = lex[(qws * 2 + 0) * 32 + ql] * __expf(mA2 - ms)
                  + lex[(qws * 2 + 1) * 32 + ql] * __expf(mB2 - ms);
        float inv = 1.f / lt;
        const float* src = oexf + qws * (32 * 258) + ql * 258 + ds0;
        float* dst = outp + base + (size_t)(q0 + q) * Cc + ds0;
#pragma unroll
        for (int i = 0; i < 16; ++i) {
            f32x4 a = *reinterpret_cast<const f32x4*>(src + 4 * i);
            a[0] *= inv; a[1] *= inv; a[2] *= inv; a[3] *= inv;
            *reinterpret_cast<f32x4*>(dst + 4 * i) = a;
        }
    }
}

extern "C" void kernel_launch(void* const* d_in, const int* in_sizes, int n_in,
                              void* d_out, int out_size, void* d_ws, size_t ws_size,
                              hipStream_t stream)
{
    (void)in_sizes; (void)n_in; (void)out_size; (void)ws_size;
    const float* x   = (const float*)d_in[0];
    const int*  mask = (const int*)d_in[1];
    const float* Wk  = (const float*)d_in[2];
    const float* Wq  = (const float*)d_in[3];
    const float* Wv  = (const float*)d_in[4];
    float* out = (float*)d_out;

    _Float16* q  = (_Float16*)d_ws;
    _Float16* k  = q + (size_t)BT * Cc;
    _Float16* vt = k + (size_t)BT * Cc;

    dim3 gA(128, 6), blkA(256);
    size_t ldsA = (size_t)(128 + 128) * 264 * sizeof(_Float16);
    qkv_proj<<<gA, blkA, ldsA, stream>>>(x, Wq, Wk, Wv, q, k, vt);

    dim3 gB(256), blkB(256);
    size_t ldsB = 74240;
    attn_kernel<<<gB, blkB, ldsB, stream>>>(q, k, vt, mask, out);
}